// Round 1
// baseline (2146.023 us; speedup 1.0000x reference)
//
#include <hip/hip_runtime.h>
#include <stdint.h>

#define SEQ 512
#define HID 512
#define GATES 2048
#define IN0 1088
#define IN1 1024
#define MLPH 100

// ---------------- zero (slots + sh/sm accumulators) ----------------
__global__ void zero_kernel(uint4* __restrict__ p, int n) {
  int i = blockIdx.x * blockDim.x + threadIdx.x;
  uint4 z = {0u, 0u, 0u, 0u};
  if (i < n) p[i] = z;
}

// ---------------- embedding gather + concat ----------------
__global__ __launch_bounds__(256) void embed_kernel(
    const int* __restrict__ widx, const int* __restrict__ pidx,
    const float* __restrict__ wemb, const float* __restrict__ pemb,
    float* __restrict__ out) {
  int t = blockIdx.x, tid = threadIdx.x;
  const float4* wsrc = (const float4*)(wemb + (size_t)widx[t] * 1024);
  float4* dst = (float4*)(out + (size_t)t * IN0);
  dst[tid] = wsrc[tid];                       // 256 float4 = 1024 floats
  if (tid < 16) {
    const float4* psrc = (const float4*)(pemb + (size_t)pidx[t] * 64);
    dst[256 + tid] = psrc[tid];               // 64 floats
  }
}

// ---------------- generic fp32 tiled GEMM: C[M,N] = A[M,K] @ Bt[N,K]^T (+bias) ----------------
// grid.x = (M/64) * ceil(N/64) * kSplit ; 256 threads; accum=1 -> atomicAdd into pre-zeroed C
__global__ __launch_bounds__(256) void gemm_kernel(
    const float* __restrict__ A, const float* __restrict__ Bt,
    const float* __restrict__ bias, float* __restrict__ C,
    int M, int N, int K, int ldb, int kSplit, int accum) {
  int ntiles = (N + 63) >> 6;
  int mtiles = M >> 6;
  int tilesPer = ntiles * mtiles;
  int bid = blockIdx.x;
  int kchunk = bid / tilesPer;
  int rem = bid - kchunk * tilesPer;
  int mt = rem / ntiles, nt = rem - mt * ntiles;
  int kLen = K / kSplit;
  int k0 = kchunk * kLen;

  __shared__ float As[16][68];
  __shared__ float Bs[16][68];
  int tid = threadIdx.x;
  int tx = tid & 15, ty = tid >> 4;
  int m0 = mt << 6, n0 = nt << 6;

  int lk4 = tid & 3;      // which float4 along K
  int lrow = tid >> 2;    // row within tile 0..63
  const float* Ap = A + (size_t)(m0 + lrow) * K + k0 + lk4 * 4;
  const float* Bp = Bt + (size_t)(n0 + lrow) * ldb + k0 + lk4 * 4;
  bool bvalid = (n0 + lrow) < N;

  float acc[4][4] = {{0.f, 0.f, 0.f, 0.f}, {0.f, 0.f, 0.f, 0.f},
                     {0.f, 0.f, 0.f, 0.f}, {0.f, 0.f, 0.f, 0.f}};

  for (int kk = 0; kk < kLen; kk += 16) {
    float4 av = *(const float4*)(Ap + kk);
    float4 bv;
    if (bvalid) bv = *(const float4*)(Bp + kk);
    else { bv.x = bv.y = bv.z = bv.w = 0.f; }
    int kbase = lk4 * 4;
    As[kbase + 0][lrow] = av.x; As[kbase + 1][lrow] = av.y;
    As[kbase + 2][lrow] = av.z; As[kbase + 3][lrow] = av.w;
    Bs[kbase + 0][lrow] = bv.x; Bs[kbase + 1][lrow] = bv.y;
    Bs[kbase + 2][lrow] = bv.z; Bs[kbase + 3][lrow] = bv.w;
    __syncthreads();
#pragma unroll
    for (int k = 0; k < 16; ++k) {
      float a[4], b[4];
      *(float4*)a = *(const float4*)&As[k][ty << 2];
      *(float4*)b = *(const float4*)&Bs[k][tx << 2];
#pragma unroll
      for (int i = 0; i < 4; ++i)
#pragma unroll
        for (int j = 0; j < 4; ++j) acc[i][j] += a[i] * b[j];
    }
    __syncthreads();
  }

#pragma unroll
  for (int i = 0; i < 4; ++i) {
    int mrow = m0 + (ty << 2) + i;
#pragma unroll
    for (int j = 0; j < 4; ++j) {
      int ncol = n0 + (tx << 2) + j;
      if (ncol < N) {
        float v = acc[i][j];
        if (accum) {
          if (kchunk == 0 && bias) v += bias[ncol];
          atomicAdd(&C[(size_t)mrow * N + ncol], v);
        } else {
          if (bias) v += bias[ncol];
          C[(size_t)mrow * N + ncol] = v;
        }
      }
    }
  }
}

// ---------------- biLSTM layer scan ----------------
// grid = 64 WGs x 256 threads. WG 0..31: forward, 32..63: backward.
// Each WG owns 16 h-elements (64 gate rows of W_hh held in VGPRs).
// h exchanged through global {epoch,value} packed u64 slots, double-buffered.
#define HBUF_WORDS 544
__device__ __forceinline__ int hb_word(int k) {
  // skewed layout: chunk c (16 floats) starts at 16c + 4*(c&7)  (16B-aligned)
  return k + (((k >> 4) & 7) << 2);
}

__global__ __launch_bounds__(256, 1) void scan_kernel(
    const float* __restrict__ whh_f, const float* __restrict__ whh_b,
    const float* __restrict__ xw_f, const float* __restrict__ xw_b,
    float* __restrict__ hout, unsigned long long* __restrict__ slots) {
  int wg = blockIdx.x;
  int dir = wg >> 5;
  int lw = wg & 31;
  int r0 = lw << 4;                 // first h index owned
  const float* whh = dir ? whh_b : whh_f;
  const float* xw = dir ? xw_b : xw_f;
  unsigned long long* slotbase = slots + (size_t)dir * 1024;  // [buf(2)][512]

  int tid = threadIdx.x;
  int cg = tid & 31;                // col group: cols cg*16..+15
  int rg = tid >> 5;                // row group: rows rg*8..+7 (of 64)

  // load W into registers: W[q][c] = whh[gate*512 + r0 + j][cg*16 + c], rr = rg*8+q = gate*16+j
  float W[8][16];
#pragma unroll
  for (int q = 0; q < 8; ++q) {
    int rr = (rg << 3) + q;
    int gate = rr >> 4, j = rr & 15;
    const float* src = whh + (size_t)(gate * 512 + r0 + j) * 512 + cg * 16;
#pragma unroll
    for (int c4 = 0; c4 < 4; ++c4) {
      float4 v = ((const float4*)src)[c4];
      W[q][c4 * 4 + 0] = v.x; W[q][c4 * 4 + 1] = v.y;
      W[q][c4 * 4 + 2] = v.z; W[q][c4 * 4 + 3] = v.w;
    }
  }

  __shared__ float hbuf[HBUF_WORDS];
  __shared__ float part[64][33];
  __shared__ float zbuf[64];
  float cstate = 0.f;  // live in threads 0..15

  for (int s = 0; s < SEQ; ++s) {
    int t = dir ? (SEQ - 1 - s) : s;

    // prefetch this step's xw value (row rr = tid for tid<64)
    float xwv = 0.f;
    if (tid < 64) {
      int gate = tid >> 4, j = tid & 15;
      xwv = xw[(size_t)t * GATES + gate * 512 + r0 + j];
    }

    // obtain h_{s-1}
    if (s == 0) {
      for (int i = tid; i < HBUF_WORDS; i += 256) hbuf[i] = 0.f;
    } else {
      unsigned long long* sb = slotbase + (size_t)((s + 1) & 1) * 512;
      unsigned long long expect = (unsigned long long)s;
      int i0 = tid * 2;
#pragma unroll
      for (int u = 0; u < 2; ++u) {
        int i = i0 + u;
        unsigned long long v;
        do {
          v = __hip_atomic_load(&sb[i], __ATOMIC_RELAXED, __HIP_MEMORY_SCOPE_AGENT);
        } while ((v >> 32) != expect);
        hbuf[hb_word(i)] = __uint_as_float((unsigned)v);
      }
    }
    __syncthreads();  // B1

    // matvec partials: 8 rows x 16 cols per thread
    float hv[16];
    int hb = (cg << 4) + ((cg & 7) << 2);
#pragma unroll
    for (int c4 = 0; c4 < 4; ++c4)
      *(float4*)&hv[c4 * 4] = *(const float4*)&hbuf[hb + c4 * 4];
#pragma unroll
    for (int q = 0; q < 8; ++q) {
      float a = 0.f;
#pragma unroll
      for (int c = 0; c < 16; ++c) a += W[q][c] * hv[c];
      part[(rg << 3) + q][cg] = a;
    }
    __syncthreads();  // B2

    if (tid < 64) {
      float sum = xwv;
#pragma unroll
      for (int g = 0; g < 32; ++g) sum += part[tid][g];
      zbuf[tid] = sum;
    }
    __syncthreads();  // B3

    if (tid < 16) {
      float zi = zbuf[tid], zf = zbuf[16 + tid], zg = zbuf[32 + tid], zo = zbuf[48 + tid];
      float ig = 1.f / (1.f + __expf(-zi));
      float fg = 1.f / (1.f + __expf(-zf));
      float og = 1.f / (1.f + __expf(-zo));
      float gg = tanhf(zg);
      cstate = fg * cstate + ig * gg;
      float h = og * tanhf(cstate);
      hout[(size_t)t * IN1 + dir * 512 + r0 + tid] = h;
      unsigned long long pub =
          (((unsigned long long)(s + 1)) << 32) | (unsigned long long)__float_as_uint(h);
      __hip_atomic_store(&slotbase[(size_t)(s & 1) * 512 + r0 + tid], pub,
                         __ATOMIC_RELAXED, __HIP_MEMORY_SCOPE_AGENT);
    }
    // no barrier needed here: next-step writes are fenced by B1/B2 participation
  }
}

// ---------------- pairwise MLP score + column softmax ----------------
// one WG per modifier column m; scores s[h] = W2 . tanh(sh[h] + smb[m]) + b2 ; softmax over h
#define SCH 128
__global__ __launch_bounds__(256) void score_kernel(
    const float* __restrict__ sh, const float* __restrict__ smb,
    const float* __restrict__ W2v, const float* __restrict__ b2,
    float* __restrict__ out) {
  int m = blockIdx.x;
  int tid = threadIdx.x;
  __shared__ float smv[MLPH];
  __shared__ float w2s[MLPH];
  __shared__ float shc[SCH][101];
  __shared__ float sbuf[512];
  __shared__ float rbuf[256];

  if (tid < MLPH) {
    smv[tid] = smb[(size_t)m * MLPH + tid];
    w2s[tid] = W2v[tid];
  }
  __syncthreads();

  int row = tid >> 1, half = tid & 1;
  float bb = b2[0];
  for (int ch = 0; ch < 4; ++ch) {
    const float* src = sh + (size_t)ch * SCH * MLPH;
    for (int i = tid; i < SCH * MLPH; i += 256) {
      int r = i / MLPH, c = i - r * MLPH;
      shc[r][c] = src[i];
    }
    __syncthreads();
    float acc = 0.f;
#pragma unroll
    for (int k = 0; k < 50; ++k) {
      int kk = half * 50 + k;
      float x = shc[row][kk] + smv[kk];
      float e = __expf(x + x);
      float th = 1.f - 2.f / (e + 1.f);
      acc += w2s[kk] * th;
    }
    acc += __shfl_xor(acc, 1);
    if (half == 0) sbuf[ch * SCH + row] = acc + bb;
    __syncthreads();
  }

  float v0 = sbuf[tid], v1 = sbuf[tid + 256];
  rbuf[tid] = fmaxf(v0, v1);
  __syncthreads();
  for (int off = 128; off > 0; off >>= 1) {
    if (tid < off) rbuf[tid] = fmaxf(rbuf[tid], rbuf[tid + off]);
    __syncthreads();
  }
  float mx = rbuf[0];
  __syncthreads();
  float e0 = __expf(v0 - mx), e1 = __expf(v1 - mx);
  rbuf[tid] = e0 + e1;
  __syncthreads();
  for (int off = 128; off > 0; off >>= 1) {
    if (tid < off) rbuf[tid] += rbuf[tid + off];
    __syncthreads();
  }
  float inv = 1.f / rbuf[0];
  out[(size_t)tid * 512 + m] = e0 * inv;
  out[(size_t)(tid + 256) * 512 + m] = e1 * inv;
}

// ---------------- launch ----------------
extern "C" void kernel_launch(void* const* d_in, const int* in_sizes, int n_in,
                              void* d_out, int out_size, void* d_ws, size_t ws_size,
                              hipStream_t stream) {
  const int* widx = (const int*)d_in[0];
  const int* pidx = (const int*)d_in[1];
  const float* wemb = (const float*)d_in[2];
  const float* pemb = (const float*)d_in[3];
  const float* wih0f = (const float*)d_in[4];
  const float* whh0f = (const float*)d_in[5];
  const float* b0f = (const float*)d_in[6];
  const float* wih0b = (const float*)d_in[7];
  const float* whh0b = (const float*)d_in[8];
  const float* b0b = (const float*)d_in[9];
  const float* wih1f = (const float*)d_in[10];
  const float* whh1f = (const float*)d_in[11];
  const float* b1f = (const float*)d_in[12];
  const float* wih1b = (const float*)d_in[13];
  const float* whh1b = (const float*)d_in[14];
  const float* b1b = (const float*)d_in[15];
  const float* W1 = (const float*)d_in[16];
  const float* b1v = (const float*)d_in[17];
  const float* W2 = (const float*)d_in[18];
  const float* b2 = (const float*)d_in[19];
  float* out = (float*)d_out;

  float* ws = (float*)d_ws;
  size_t off = 0;
  float* embeds = ws + off; off += (size_t)SEQ * IN0;
  float* xw0f = ws + off; off += (size_t)SEQ * GATES;
  float* xw0b = ws + off; off += (size_t)SEQ * GATES;
  float* xw1f = ws + off; off += (size_t)SEQ * GATES;
  float* xw1b = ws + off; off += (size_t)SEQ * GATES;
  float* h0 = ws + off; off += (size_t)SEQ * IN1;
  float* h1 = ws + off; off += (size_t)SEQ * IN1;
  float* shb = ws + off; off += (size_t)SEQ * MLPH;
  float* smb = ws + off; off += (size_t)SEQ * MLPH;
  unsigned long long* slots0 = (unsigned long long*)(ws + off);
  unsigned long long* slots1 = slots0 + 2048;
  size_t total_bytes = off * 4 + 4096ull * 8;
  if (ws_size < total_bytes) return;

  // zero sh, smb (atomic accumulators) and both slot arrays — contiguous from shb
  size_t zero_bytes = (size_t)SEQ * MLPH * 2 * 4 + 4096ull * 8;
  int n16 = (int)(zero_bytes / 16);
  zero_kernel<<<(n16 + 255) / 256, 256, 0, stream>>>((uint4*)shb, n16);

  embed_kernel<<<SEQ, 256, 0, stream>>>(widx, pidx, wemb, pemb, embeds);

  // layer-0 input projections: [512,1088] @ [2048,1088]^T
  gemm_kernel<<<8 * 32, 256, 0, stream>>>(embeds, wih0f, b0f, xw0f, SEQ, GATES, IN0, IN0, 1, 0);
  gemm_kernel<<<8 * 32, 256, 0, stream>>>(embeds, wih0b, b0b, xw0b, SEQ, GATES, IN0, IN0, 1, 0);

  scan_kernel<<<64, 256, 0, stream>>>(whh0f, whh0b, xw0f, xw0b, h0, slots0);

  // layer-1 input projections: [512,1024] @ [2048,1024]^T
  gemm_kernel<<<8 * 32, 256, 0, stream>>>(h0, wih1f, b1f, xw1f, SEQ, GATES, IN1, IN1, 1, 0);
  gemm_kernel<<<8 * 32, 256, 0, stream>>>(h0, wih1b, b1b, xw1b, SEQ, GATES, IN1, IN1, 1, 0);

  scan_kernel<<<64, 256, 0, stream>>>(whh1f, whh1b, xw1f, xw1b, h1, slots1);

  // MLP projections (split-K=8, atomicAdd): sh = h1 @ W1[:,:1024]^T ; smb = h1 @ W1[:,1024:]^T + b1
  gemm_kernel<<<8 * 2 * 8, 256, 0, stream>>>(h1, W1, nullptr, shb, SEQ, MLPH, IN1, 2048, 8, 1);
  gemm_kernel<<<8 * 2 * 8, 256, 0, stream>>>(h1, W1 + 1024, b1v, smb, SEQ, MLPH, IN1, 2048, 8, 1);

  score_kernel<<<SEQ, 256, 0, stream>>>(shb, smb, W2, b2, out);
}